// Round 2
// baseline (972.386 us; speedup 1.0000x reference)
//
#include <hip/hip_runtime.h>

// ---------- types & helpers ----------
typedef __attribute__((ext_vector_type(8))) short sh8;   // 8 x bf16 (4 VGPRs)
typedef __attribute__((ext_vector_type(4))) float f4;    // MFMA accum / float4

__device__ __forceinline__ float bf2f(unsigned short u) {
    union { unsigned int u; float f; } c; c.u = ((unsigned int)u) << 16; return c.f;
}
__device__ __forceinline__ unsigned short f2bf(float f) {
    union { float f; unsigned int u; } c; c.f = f;
    unsigned int x = c.u;
    unsigned int r = (x + 0x7fffu + ((x >> 16) & 1u)) >> 16;   // RNE
    return (unsigned short)r;
}
// split fp32 into bf16 hi + bf16 lo (residual)
__device__ __forceinline__ void bfsplit(float x, short& hi, short& lo) {
    unsigned short h = f2bf(x);
    float r = x - bf2f(h);
    hi = (short)h;
    lo = (short)f2bf(r);
}

// ---------- CSR build ----------
__global__ void k_zero_cnt(int* cnt, int N) {
    int i = blockIdx.x * 256 + threadIdx.x;
    if (i < N) cnt[i] = 0;
}

__global__ void k_count(const int* __restrict__ src, const int* __restrict__ dst,
                        int* __restrict__ cnt, int E, int N) {
    int e = blockIdx.x * 256 + threadIdx.x;
    if (e >= E) return;
    int s = src[e], d = dst[e];
    if ((unsigned)s < (unsigned)N && (unsigned)d < (unsigned)N) atomicAdd(&cnt[d], 1);
}

__global__ void k_dis(const int* __restrict__ cnt, float* __restrict__ dis, int N) {
    int i = blockIdx.x * 256 + threadIdx.x;
    if (i < N) dis[i] = rsqrtf((float)(cnt[i] + 1));   // +1 self loop; deg>=1 always
}

#define SCAN_B 256
__global__ void k_scan_a(const int* __restrict__ cnt, int* __restrict__ rowptr,
                         int* __restrict__ bsum, int N) {
    __shared__ int sh[SCAN_B];
    int t = threadIdx.x, i = blockIdx.x * SCAN_B + t;
    int v = (i < N) ? cnt[i] : 0;
    sh[t] = v; __syncthreads();
    for (int off = 1; off < SCAN_B; off <<= 1) {
        int x = (t >= off) ? sh[t - off] : 0;
        __syncthreads();
        sh[t] += x;
        __syncthreads();
    }
    int incl = sh[t];
    if (i < N) rowptr[i] = incl - v;                 // exclusive within block
    if (t == SCAN_B - 1) bsum[blockIdx.x] = incl;    // block total
}

__global__ void k_scan_b(int* bsum, int NB) {
    __shared__ int sh[512];
    int t = threadIdx.x;
    int v = (t < NB) ? bsum[t] : 0;
    sh[t] = v; __syncthreads();
    for (int off = 1; off < 512; off <<= 1) {
        int x = (t >= off) ? sh[t - off] : 0;
        __syncthreads();
        sh[t] += x;
        __syncthreads();
    }
    if (t < NB) bsum[t] = sh[t] - v;                 // exclusive block offsets
}

__global__ void k_scan_c(int* __restrict__ rowptr, int* __restrict__ cursor,
                         const int* __restrict__ bsum, int N) {
    int i = blockIdx.x * 256 + threadIdx.x;
    if (i < N) {
        int r = rowptr[i] + bsum[blockIdx.x];
        rowptr[i] = r;
        cursor[i] = r;
    }
}

__global__ void k_fill(const int* __restrict__ src, const int* __restrict__ dst,
                       int* __restrict__ cursor, int* __restrict__ csr_src, int E, int N) {
    int e = blockIdx.x * 256 + threadIdx.x;
    if (e >= E) return;
    int s = src[e], d = dst[e];
    if ((unsigned)s >= (unsigned)N || (unsigned)d >= (unsigned)N) return;
    int p = atomicAdd(&cursor[d], 1);
    csr_src[p] = s;
}

// ---------- GEMM: H[N][128] = X[N][128] @ W[128][128]  (fp32 in/out, split-bf16 MFMA) ----------
// Block = 256 threads = 4 waves. wave&1 -> column half (64 cols), wave>>1 -> node subtile.
// W split into bf16 hi/lo fragments, register-resident. XW ~= Xh*Wh + Xh*Wl + Xl*Wh (fp32 accum).
__global__ __launch_bounds__(256)
void k_gemm128(const float* __restrict__ X,
               const float* __restrict__ W,
               float* __restrict__ H, int nPairs) {
    int wave = threadIdx.x >> 6;
    int lane = threadIdx.x & 63;
    int ln = lane & 15, quad = lane >> 4;
    int c0 = (wave & 1) * 64;
    int subTile = wave >> 1;

    sh8 bh[4][4], blo[4][4];   // [nt][kt]
    #pragma unroll
    for (int nt = 0; nt < 4; ++nt) {
        int col = c0 + nt * 16 + ln;
        #pragma unroll
        for (int kt = 0; kt < 4; ++kt) {
            int k0 = kt * 32 + quad * 8;
            #pragma unroll
            for (int j = 0; j < 8; ++j) {
                short h, l;
                bfsplit(W[(k0 + j) * 128 + col], h, l);
                bh[nt][kt][j] = h; blo[nt][kt][j] = l;
            }
        }
    }

    for (int p = blockIdx.x; p < nPairs; p += gridDim.x) {
        int nodeBase = p * 32 + subTile * 16;
        const float* xrow = X + (nodeBase + ln) * 128 + quad * 8;
        sh8 ah[4], al[4];
        #pragma unroll
        for (int kt = 0; kt < 4; ++kt) {
            f4 v0 = *(const f4*)(xrow + kt * 32);
            f4 v1 = *(const f4*)(xrow + kt * 32 + 4);
            #pragma unroll
            for (int j = 0; j < 4; ++j) {
                short h, l;
                bfsplit(v0[j], h, l); ah[kt][j] = h; al[kt][j] = l;
                bfsplit(v1[j], h, l); ah[kt][j + 4] = h; al[kt][j + 4] = l;
            }
        }

        f4 acc[4] = { {0.f,0.f,0.f,0.f}, {0.f,0.f,0.f,0.f}, {0.f,0.f,0.f,0.f}, {0.f,0.f,0.f,0.f} };
        #pragma unroll
        for (int kt = 0; kt < 4; ++kt)
            #pragma unroll
            for (int nt = 0; nt < 4; ++nt) {
                acc[nt] = __builtin_amdgcn_mfma_f32_16x16x32_bf16(ah[kt], bh[nt][kt], acc[nt], 0, 0, 0);
                acc[nt] = __builtin_amdgcn_mfma_f32_16x16x32_bf16(ah[kt], blo[nt][kt], acc[nt], 0, 0, 0);
                acc[nt] = __builtin_amdgcn_mfma_f32_16x16x32_bf16(al[kt], bh[nt][kt], acc[nt], 0, 0, 0);
            }

        #pragma unroll
        for (int nt = 0; nt < 4; ++nt) {
            int col = c0 + nt * 16 + ln;
            #pragma unroll
            for (int r = 0; r < 4; ++r) {
                int row = nodeBase + quad * 4 + r;
                H[row * 128 + col] = acc[nt][r];
            }
        }
    }
}

// ---------- Aggregation: O[n] = bias + relu?( sum_{e in csr(n)} dis[s]*dis[n] * H[s] + dis[n]^2 * H[n] ) ----------
// One wave per node; 64 lanes x 2 fp32 features. fp32 accumulation throughout.
__global__ __launch_bounds__(256)
void k_agg(const float* __restrict__ H,
           float* __restrict__ O,
           const float* __restrict__ dis,
           const int* __restrict__ rowptr,
           const int* __restrict__ cnt,
           const int* __restrict__ csr_src,
           const float* __restrict__ bias,
           int relu, int N) {
    int n = (blockIdx.x * 256 + threadIdx.x) >> 6;
    int lane = threadIdx.x & 63;
    if (n >= N) return;
    int c = lane * 2;

    float dn = dis[n];
    float a0 = H[n * 128 + c]     * dn * dn;
    float a1 = H[n * 128 + c + 1] * dn * dn;

    int start = rowptr[n];
    int e = cnt[n];
    for (int i = 0; i < e; ++i) {
        int s = csr_src[start + i];
        if ((unsigned)s >= (unsigned)N) continue;   // safety: never gather wild
        float w = dis[s] * dn;
        a0 += w * H[s * 128 + c];
        a1 += w * H[s * 128 + c + 1];
    }

    a0 += bias[c];
    a1 += bias[c + 1];
    if (relu) { a0 = fmaxf(a0, 0.f); a1 = fmaxf(a1, 0.f); }

    O[n * 128 + c]     = a0;
    O[n * 128 + c + 1] = a1;
}

// ---------- Final head: OUT[N][40] = X[N][128] @ Wl[128][40] + bl  (pad cols to 48) ----------
__global__ __launch_bounds__(256)
void k_gemm_final(const float* __restrict__ X,
                  const float* __restrict__ W,     // [128][40]
                  const float* __restrict__ bl,    // [40]
                  float* __restrict__ OUT, int nTiles) {
    int wave = threadIdx.x >> 6;
    int lane = threadIdx.x & 63;
    int ln = lane & 15, quad = lane >> 4;
    int tile = blockIdx.x * 4 + wave;
    if (tile >= nTiles) return;

    sh8 bh[3][4], blo[3][4];
    #pragma unroll
    for (int nt = 0; nt < 3; ++nt) {
        int col = nt * 16 + ln;
        bool valid = (col < 40);
        #pragma unroll
        for (int kt = 0; kt < 4; ++kt) {
            int k0 = kt * 32 + quad * 8;
            #pragma unroll
            for (int j = 0; j < 8; ++j) {
                short h = 0, l = 0;
                if (valid) bfsplit(W[(k0 + j) * 40 + col], h, l);
                bh[nt][kt][j] = h; blo[nt][kt][j] = l;
            }
        }
    }

    int nodeBase = tile * 16;
    const float* xrow = X + (nodeBase + ln) * 128 + quad * 8;
    sh8 ah[4], al[4];
    #pragma unroll
    for (int kt = 0; kt < 4; ++kt) {
        f4 v0 = *(const f4*)(xrow + kt * 32);
        f4 v1 = *(const f4*)(xrow + kt * 32 + 4);
        #pragma unroll
        for (int j = 0; j < 4; ++j) {
            short h, l;
            bfsplit(v0[j], h, l); ah[kt][j] = h; al[kt][j] = l;
            bfsplit(v1[j], h, l); ah[kt][j + 4] = h; al[kt][j + 4] = l;
        }
    }

    f4 acc[3] = { {0.f,0.f,0.f,0.f}, {0.f,0.f,0.f,0.f}, {0.f,0.f,0.f,0.f} };
    #pragma unroll
    for (int kt = 0; kt < 4; ++kt)
        #pragma unroll
        for (int nt = 0; nt < 3; ++nt) {
            acc[nt] = __builtin_amdgcn_mfma_f32_16x16x32_bf16(ah[kt], bh[nt][kt], acc[nt], 0, 0, 0);
            acc[nt] = __builtin_amdgcn_mfma_f32_16x16x32_bf16(ah[kt], blo[nt][kt], acc[nt], 0, 0, 0);
            acc[nt] = __builtin_amdgcn_mfma_f32_16x16x32_bf16(al[kt], bh[nt][kt], acc[nt], 0, 0, 0);
        }

    #pragma unroll
    for (int nt = 0; nt < 3; ++nt) {
        int col = nt * 16 + ln;
        if (col < 40) {
            float bv = bl[col];
            #pragma unroll
            for (int r = 0; r < 4; ++r) {
                int row = nodeBase + quad * 4 + r;
                OUT[row * 40 + col] = acc[nt][r] + bv;
            }
        }
    }
}

// ---------- launch ----------
extern "C" void kernel_launch(void* const* d_in, const int* in_sizes, int n_in,
                              void* d_out, int out_size, void* d_ws, size_t ws_size,
                              hipStream_t stream) {
    const float* x  = (const float*)d_in[0];
    const int*   ei = (const int*)d_in[1];
    const float* W1 = (const float*)d_in[2];
    const float* b1 = (const float*)d_in[3];
    const float* W2 = (const float*)d_in[4];
    const float* b2 = (const float*)d_in[5];
    const float* W3 = (const float*)d_in[6];
    const float* b3 = (const float*)d_in[7];
    const float* Wl = (const float*)d_in[8];
    const float* bl = (const float*)d_in[9];

    const int N = in_sizes[0] / 128;   // 100000
    const int E = in_sizes[1] / 2;     // 1600000
    const int* srcIdx = ei;
    const int* dstIdx = ei + E;

    char* ws = (char*)d_ws;
    size_t off = 0;
    auto alloc = [&](size_t bytes) { void* p = ws + off; off += (bytes + 511) & ~(size_t)511; return p; };
    int*   cnt     = (int*)  alloc((size_t)N * 4);
    int*   rowptr  = (int*)  alloc((size_t)N * 4);
    int*   cursor  = (int*)  alloc((size_t)N * 4);
    float* dis     = (float*)alloc((size_t)N * 4);
    int*   bsum    = (int*)  alloc(512 * 4);
    int*   csr_src = (int*)  alloc((size_t)E * 4);
    float* h0      = (float*)alloc((size_t)N * 128 * 4);
    float* h1      = (float*)alloc((size_t)N * 128 * 4);

    const int gN = (N + 255) / 256;           // 391
    const int gE = (E + 255) / 256;           // 6250
    const int nPairs = N / 32;                // 3125 (N divisible by 32)
    const int nTiles = N / 16;                // 6250
    const int gAgg = (N * 64) / 256;          // 25000

    // CSR build
    k_zero_cnt<<<gN, 256, 0, stream>>>(cnt, N);
    k_count<<<gE, 256, 0, stream>>>(srcIdx, dstIdx, cnt, E, N);
    k_dis<<<gN, 256, 0, stream>>>(cnt, dis, N);
    k_scan_a<<<gN, 256, 0, stream>>>(cnt, rowptr, bsum, N);
    k_scan_b<<<1, 512, 0, stream>>>(bsum, gN);
    k_scan_c<<<gN, 256, 0, stream>>>(rowptr, cursor, bsum, N);
    k_fill<<<gE, 256, 0, stream>>>(srcIdx, dstIdx, cursor, csr_src, E, N);

    // Layer 1: h1 = relu(Agg(x @ W1) + b1)
    k_gemm128<<<768, 256, 0, stream>>>(x, W1, h0, nPairs);
    k_agg<<<gAgg, 256, 0, stream>>>(h0, h1, dis, rowptr, cnt, csr_src, b1, 1, N);
    // Layer 2
    k_gemm128<<<768, 256, 0, stream>>>(h1, W2, h0, nPairs);
    k_agg<<<gAgg, 256, 0, stream>>>(h0, h1, dis, rowptr, cnt, csr_src, b2, 1, N);
    // Layer 3 (no relu)
    k_gemm128<<<768, 256, 0, stream>>>(h1, W3, h0, nPairs);
    k_agg<<<gAgg, 256, 0, stream>>>(h0, h1, dis, rowptr, cnt, csr_src, b3, 0, N);
    // Head
    k_gemm_final<<<(nTiles + 3) / 4, 256, 0, stream>>>(h1, Wl, bl, (float*)d_out, nTiles);
}

// Round 3
// 658.890 us; speedup vs baseline: 1.4758x; 1.4758x over previous
//
#include <hip/hip_runtime.h>

// ---------- types & helpers ----------
typedef __attribute__((ext_vector_type(8))) short sh8;   // 8 x bf16 (4 VGPRs)
typedef __attribute__((ext_vector_type(4))) float f4;    // MFMA accum / float4

__device__ __forceinline__ float bf2f(unsigned short u) {
    union { unsigned int u; float f; } c; c.u = ((unsigned int)u) << 16; return c.f;
}
__device__ __forceinline__ unsigned short f2bf(float f) {
    union { float f; unsigned int u; } c; c.f = f;
    unsigned int x = c.u;
    unsigned int r = (x + 0x7fffu + ((x >> 16) & 1u)) >> 16;   // RNE
    return (unsigned short)r;
}
// split fp32 into bf16 hi + bf16 lo (residual)
__device__ __forceinline__ void bfsplit(float x, short& hi, short& lo) {
    unsigned short h = f2bf(x);
    float r = x - bf2f(h);
    hi = (short)h;
    lo = (short)f2bf(r);
}

struct Ent { int s; float w; };   // 8B: src index + edge weight dis[s]*dis[d]

// ---------- CSR build ----------
__global__ void k_zero_cnt(int* cnt, int N) {
    int i = blockIdx.x * 256 + threadIdx.x;
    if (i < N) cnt[i] = 0;
}

__global__ void k_count(const int* __restrict__ src, const int* __restrict__ dst,
                        int* __restrict__ cnt, int E, int N) {
    int e = blockIdx.x * 256 + threadIdx.x;
    if (e >= E) return;
    int s = src[e], d = dst[e];
    if ((unsigned)s < (unsigned)N && (unsigned)d < (unsigned)N) atomicAdd(&cnt[d], 1);
}

__global__ void k_dis(const int* __restrict__ cnt, float* __restrict__ dis, int N) {
    int i = blockIdx.x * 256 + threadIdx.x;
    if (i < N) dis[i] = rsqrtf((float)(cnt[i] + 1));   // +1 self loop
}

#define SCAN_B 256
__global__ void k_scan_a(const int* __restrict__ cnt, int* __restrict__ rowptr,
                         int* __restrict__ bsum, int N) {
    __shared__ int sh[SCAN_B];
    int t = threadIdx.x, i = blockIdx.x * SCAN_B + t;
    int v = (i < N) ? cnt[i] : 0;
    sh[t] = v; __syncthreads();
    for (int off = 1; off < SCAN_B; off <<= 1) {
        int x = (t >= off) ? sh[t - off] : 0;
        __syncthreads();
        sh[t] += x;
        __syncthreads();
    }
    int incl = sh[t];
    if (i < N) rowptr[i] = incl - v;
    if (t == SCAN_B - 1) bsum[blockIdx.x] = incl;
}

__global__ void k_scan_b(int* bsum, int NB) {
    __shared__ int sh[512];
    int t = threadIdx.x;
    int v = (t < NB) ? bsum[t] : 0;
    sh[t] = v; __syncthreads();
    for (int off = 1; off < 512; off <<= 1) {
        int x = (t >= off) ? sh[t - off] : 0;
        __syncthreads();
        sh[t] += x;
        __syncthreads();
    }
    if (t < NB) bsum[t] = sh[t] - v;
}

__global__ void k_scan_c(int* __restrict__ rowptr, int* __restrict__ cursor,
                         const int* __restrict__ bsum, int N) {
    int i = blockIdx.x * 256 + threadIdx.x;
    if (i < N) {
        int r = rowptr[i] + bsum[blockIdx.x];
        rowptr[i] = r;
        cursor[i] = r;
    }
}

__global__ void k_fill(const int* __restrict__ src, const int* __restrict__ dst,
                       const float* __restrict__ dis, int* __restrict__ cursor,
                       Ent* __restrict__ ent, int E, int N) {
    int e = blockIdx.x * 256 + threadIdx.x;
    if (e >= E) return;
    int s = src[e], d = dst[e];
    if ((unsigned)s >= (unsigned)N || (unsigned)d >= (unsigned)N) return;
    int p = atomicAdd(&cursor[d], 1);
    Ent en; en.s = s; en.w = dis[s] * dis[d];
    ent[p] = en;
}

// ---------- GEMM (layer 1): H[N][128](bf16) = X[N][128](fp32) @ W[128][128](fp32) ----------
// split-A + split-B: Xh*Wh + Xh*Wl + Xl*Wh, fp32 accum, bf16 store.
__global__ __launch_bounds__(256)
void k_gemm128_a32(const float* __restrict__ X,
                   const float* __restrict__ W,
                   unsigned short* __restrict__ H, int nPairs) {
    int wave = threadIdx.x >> 6;
    int lane = threadIdx.x & 63;
    int ln = lane & 15, quad = lane >> 4;
    int c0 = (wave & 1) * 64;
    int subTile = wave >> 1;

    sh8 bh[4][4], blo[4][4];   // [nt][kt]
    #pragma unroll
    for (int nt = 0; nt < 4; ++nt) {
        int col = c0 + nt * 16 + ln;
        #pragma unroll
        for (int kt = 0; kt < 4; ++kt) {
            int k0 = kt * 32 + quad * 8;
            #pragma unroll
            for (int j = 0; j < 8; ++j) {
                short h, l;
                bfsplit(W[(k0 + j) * 128 + col], h, l);
                bh[nt][kt][j] = h; blo[nt][kt][j] = l;
            }
        }
    }

    for (int p = blockIdx.x; p < nPairs; p += gridDim.x) {
        int nodeBase = p * 32 + subTile * 16;
        const float* xrow = X + (nodeBase + ln) * 128 + quad * 8;
        sh8 ah[4], al[4];
        #pragma unroll
        for (int kt = 0; kt < 4; ++kt) {
            f4 v0 = *(const f4*)(xrow + kt * 32);
            f4 v1 = *(const f4*)(xrow + kt * 32 + 4);
            #pragma unroll
            for (int j = 0; j < 4; ++j) {
                short h, l;
                bfsplit(v0[j], h, l); ah[kt][j] = h; al[kt][j] = l;
                bfsplit(v1[j], h, l); ah[kt][j + 4] = h; al[kt][j + 4] = l;
            }
        }

        f4 acc[4] = { {0.f,0.f,0.f,0.f}, {0.f,0.f,0.f,0.f}, {0.f,0.f,0.f,0.f}, {0.f,0.f,0.f,0.f} };
        #pragma unroll
        for (int kt = 0; kt < 4; ++kt)
            #pragma unroll
            for (int nt = 0; nt < 4; ++nt) {
                acc[nt] = __builtin_amdgcn_mfma_f32_16x16x32_bf16(ah[kt], bh[nt][kt], acc[nt], 0, 0, 0);
                acc[nt] = __builtin_amdgcn_mfma_f32_16x16x32_bf16(ah[kt], blo[nt][kt], acc[nt], 0, 0, 0);
                acc[nt] = __builtin_amdgcn_mfma_f32_16x16x32_bf16(al[kt], bh[nt][kt], acc[nt], 0, 0, 0);
            }

        #pragma unroll
        for (int nt = 0; nt < 4; ++nt) {
            int col = c0 + nt * 16 + ln;
            #pragma unroll
            for (int r = 0; r < 4; ++r)
                H[(nodeBase + quad * 4 + r) * 128 + col] = f2bf(acc[nt][r]);
        }
    }
}

// ---------- GEMM (layers 2,3): H(bf16) = X(bf16) @ W(fp32, split) ----------
__global__ __launch_bounds__(256)
void k_gemm128_a16(const unsigned short* __restrict__ X,
                   const float* __restrict__ W,
                   unsigned short* __restrict__ H, int nPairs) {
    int wave = threadIdx.x >> 6;
    int lane = threadIdx.x & 63;
    int ln = lane & 15, quad = lane >> 4;
    int c0 = (wave & 1) * 64;
    int subTile = wave >> 1;

    sh8 bh[4][4], blo[4][4];
    #pragma unroll
    for (int nt = 0; nt < 4; ++nt) {
        int col = c0 + nt * 16 + ln;
        #pragma unroll
        for (int kt = 0; kt < 4; ++kt) {
            int k0 = kt * 32 + quad * 8;
            #pragma unroll
            for (int j = 0; j < 8; ++j) {
                short h, l;
                bfsplit(W[(k0 + j) * 128 + col], h, l);
                bh[nt][kt][j] = h; blo[nt][kt][j] = l;
            }
        }
    }

    for (int p = blockIdx.x; p < nPairs; p += gridDim.x) {
        int nodeBase = p * 32 + subTile * 16;
        const unsigned short* xrow = X + (nodeBase + ln) * 128 + quad * 8;
        sh8 a[4];
        #pragma unroll
        for (int kt = 0; kt < 4; ++kt) a[kt] = *(const sh8*)(xrow + kt * 32);

        f4 acc[4] = { {0.f,0.f,0.f,0.f}, {0.f,0.f,0.f,0.f}, {0.f,0.f,0.f,0.f}, {0.f,0.f,0.f,0.f} };
        #pragma unroll
        for (int kt = 0; kt < 4; ++kt)
            #pragma unroll
            for (int nt = 0; nt < 4; ++nt) {
                acc[nt] = __builtin_amdgcn_mfma_f32_16x16x32_bf16(a[kt], bh[nt][kt], acc[nt], 0, 0, 0);
                acc[nt] = __builtin_amdgcn_mfma_f32_16x16x32_bf16(a[kt], blo[nt][kt], acc[nt], 0, 0, 0);
            }

        #pragma unroll
        for (int nt = 0; nt < 4; ++nt) {
            int col = c0 + nt * 16 + ln;
            #pragma unroll
            for (int r = 0; r < 4; ++r)
                H[(nodeBase + quad * 4 + r) * 128 + col] = f2bf(acc[nt][r]);
        }
    }
}

// ---------- Aggregation: O(bf16) = bias + relu?( sum_e w_e * H[s_e] + dis[n]^2 * H[n] ) ----------
// One wave/node, 64 lanes x 2 bf16 feats (uint), fp32 accum, 2-edge pipelined loop.
__global__ __launch_bounds__(256)
void k_agg(const unsigned short* __restrict__ H,
           unsigned short* __restrict__ O,
           const float* __restrict__ dis,
           const int* __restrict__ rowptr,
           const int* __restrict__ cnt,
           const Ent* __restrict__ ent,
           const float* __restrict__ bias,
           int relu, int N) {
    int n = (blockIdx.x * 256 + threadIdx.x) >> 6;
    int lane = threadIdx.x & 63;
    if (n >= N) return;
    int c = lane * 2;

    float dn = dis[n];
    unsigned int hv = *(const unsigned int*)(H + n * 128 + c);
    float a0 = bf2f((unsigned short)hv) * dn * dn;
    float a1 = bf2f((unsigned short)(hv >> 16)) * dn * dn;

    int start = rowptr[n];
    int e = cnt[n];
    int i = 0;
    for (; i + 2 <= e; i += 2) {
        Ent e0 = ent[start + i];
        Ent e1 = ent[start + i + 1];
        unsigned int v0 = *(const unsigned int*)(H + (size_t)e0.s * 128 + c);
        unsigned int v1 = *(const unsigned int*)(H + (size_t)e1.s * 128 + c);
        a0 += e0.w * bf2f((unsigned short)v0);
        a1 += e0.w * bf2f((unsigned short)(v0 >> 16));
        a0 += e1.w * bf2f((unsigned short)v1);
        a1 += e1.w * bf2f((unsigned short)(v1 >> 16));
    }
    if (i < e) {
        Ent e0 = ent[start + i];
        unsigned int v0 = *(const unsigned int*)(H + (size_t)e0.s * 128 + c);
        a0 += e0.w * bf2f((unsigned short)v0);
        a1 += e0.w * bf2f((unsigned short)(v0 >> 16));
    }

    a0 += bias[c];
    a1 += bias[c + 1];
    if (relu) { a0 = fmaxf(a0, 0.f); a1 = fmaxf(a1, 0.f); }

    unsigned int ov = (unsigned int)f2bf(a0) | ((unsigned int)f2bf(a1) << 16);
    *(unsigned int*)(O + n * 128 + c) = ov;
}

// ---------- Final head: OUT[N][40](fp32) = X(bf16) @ Wl(fp32 split) + bl ----------
__global__ __launch_bounds__(256)
void k_gemm_final(const unsigned short* __restrict__ X,
                  const float* __restrict__ W,     // [128][40]
                  const float* __restrict__ bl,    // [40]
                  float* __restrict__ OUT, int nTiles) {
    int wave = threadIdx.x >> 6;
    int lane = threadIdx.x & 63;
    int ln = lane & 15, quad = lane >> 4;
    int tile = blockIdx.x * 4 + wave;
    if (tile >= nTiles) return;

    sh8 bh[3][4], blo[3][4];
    #pragma unroll
    for (int nt = 0; nt < 3; ++nt) {
        int col = nt * 16 + ln;
        bool valid = (col < 40);
        #pragma unroll
        for (int kt = 0; kt < 4; ++kt) {
            int k0 = kt * 32 + quad * 8;
            #pragma unroll
            for (int j = 0; j < 8; ++j) {
                short h = 0, l = 0;
                if (valid) bfsplit(W[(k0 + j) * 40 + col], h, l);
                bh[nt][kt][j] = h; blo[nt][kt][j] = l;
            }
        }
    }

    int nodeBase = tile * 16;
    const unsigned short* xrow = X + (nodeBase + ln) * 128 + quad * 8;
    sh8 a[4];
    #pragma unroll
    for (int kt = 0; kt < 4; ++kt) a[kt] = *(const sh8*)(xrow + kt * 32);

    f4 acc[3] = { {0.f,0.f,0.f,0.f}, {0.f,0.f,0.f,0.f}, {0.f,0.f,0.f,0.f} };
    #pragma unroll
    for (int kt = 0; kt < 4; ++kt)
        #pragma unroll
        for (int nt = 0; nt < 3; ++nt) {
            acc[nt] = __builtin_amdgcn_mfma_f32_16x16x32_bf16(a[kt], bh[nt][kt], acc[nt], 0, 0, 0);
            acc[nt] = __builtin_amdgcn_mfma_f32_16x16x32_bf16(a[kt], blo[nt][kt], acc[nt], 0, 0, 0);
        }

    #pragma unroll
    for (int nt = 0; nt < 3; ++nt) {
        int col = nt * 16 + ln;
        if (col < 40) {
            float bv = bl[col];
            #pragma unroll
            for (int r = 0; r < 4; ++r)
                OUT[(nodeBase + quad * 4 + r) * 40 + col] = acc[nt][r] + bv;
        }
    }
}

// ---------- launch ----------
extern "C" void kernel_launch(void* const* d_in, const int* in_sizes, int n_in,
                              void* d_out, int out_size, void* d_ws, size_t ws_size,
                              hipStream_t stream) {
    const float* x  = (const float*)d_in[0];
    const int*   ei = (const int*)d_in[1];
    const float* W1 = (const float*)d_in[2];
    const float* b1 = (const float*)d_in[3];
    const float* W2 = (const float*)d_in[4];
    const float* b2 = (const float*)d_in[5];
    const float* W3 = (const float*)d_in[6];
    const float* b3 = (const float*)d_in[7];
    const float* Wl = (const float*)d_in[8];
    const float* bl = (const float*)d_in[9];

    const int N = in_sizes[0] / 128;   // 100000
    const int E = in_sizes[1] / 2;     // 1600000
    const int* srcIdx = ei;
    const int* dstIdx = ei + E;

    char* ws = (char*)d_ws;
    size_t off = 0;
    auto alloc = [&](size_t bytes) { void* p = ws + off; off += (bytes + 511) & ~(size_t)511; return p; };
    int*   cnt     = (int*)  alloc((size_t)N * 4);
    int*   rowptr  = (int*)  alloc((size_t)N * 4);
    int*   cursor  = (int*)  alloc((size_t)N * 4);
    float* dis     = (float*)alloc((size_t)N * 4);
    int*   bsum    = (int*)  alloc(512 * 4);
    Ent*   ent     = (Ent*)  alloc((size_t)E * 8);
    unsigned short* h0 = (unsigned short*)alloc((size_t)N * 128 * 2);
    unsigned short* h1 = (unsigned short*)alloc((size_t)N * 128 * 2);

    const int gN = (N + 255) / 256;           // 391
    const int gE = (E + 255) / 256;           // 6250
    const int nPairs = N / 32;                // 3125
    const int nTiles = N / 16;                // 6250
    const int gAgg = (N * 64) / 256;          // 25000

    // CSR build
    k_zero_cnt<<<gN, 256, 0, stream>>>(cnt, N);
    k_count<<<gE, 256, 0, stream>>>(srcIdx, dstIdx, cnt, E, N);
    k_dis<<<gN, 256, 0, stream>>>(cnt, dis, N);
    k_scan_a<<<gN, 256, 0, stream>>>(cnt, rowptr, bsum, N);
    k_scan_b<<<1, 512, 0, stream>>>(bsum, gN);
    k_scan_c<<<gN, 256, 0, stream>>>(rowptr, cursor, bsum, N);
    k_fill<<<gE, 256, 0, stream>>>(srcIdx, dstIdx, dis, cursor, ent, E, N);

    // Layer 1
    k_gemm128_a32<<<768, 256, 0, stream>>>(x, W1, h0, nPairs);
    k_agg<<<gAgg, 256, 0, stream>>>(h0, h1, dis, rowptr, cnt, ent, b1, 1, N);
    // Layer 2
    k_gemm128_a16<<<768, 256, 0, stream>>>(h1, W2, h0, nPairs);
    k_agg<<<gAgg, 256, 0, stream>>>(h0, h1, dis, rowptr, cnt, ent, b2, 1, N);
    // Layer 3 (no relu)
    k_gemm128_a16<<<768, 256, 0, stream>>>(h1, W3, h0, nPairs);
    k_agg<<<gAgg, 256, 0, stream>>>(h0, h1, dis, rowptr, cnt, ent, b3, 0, N);
    // Head
    k_gemm_final<<<(nTiles + 3) / 4, 256, 0, stream>>>(h1, Wl, bl, (float*)d_out, nTiles);
}

// Round 4
// 615.158 us; speedup vs baseline: 1.5807x; 1.0711x over previous
//
#include <hip/hip_runtime.h>

// ---------- types & helpers ----------
typedef __attribute__((ext_vector_type(8))) short sh8;   // 8 x bf16 (4 VGPRs)
typedef __attribute__((ext_vector_type(4))) float f4;    // MFMA accum / float4

__device__ __forceinline__ float bf2f(unsigned short u) {
    union { unsigned int u; float f; } c; c.u = ((unsigned int)u) << 16; return c.f;
}
__device__ __forceinline__ unsigned short f2bf(float f) {
    union { float f; unsigned int u; } c; c.f = f;
    unsigned int x = c.u;
    unsigned int r = (x + 0x7fffu + ((x >> 16) & 1u)) >> 16;   // RNE
    return (unsigned short)r;
}
// split fp32 into bf16 hi + bf16 lo (residual)
__device__ __forceinline__ void bfsplit(float x, short& hi, short& lo) {
    unsigned short h = f2bf(x);
    float r = x - bf2f(h);
    hi = (short)h;
    lo = (short)f2bf(r);
}

// ---------- CSR build ----------
__global__ void k_zero_cnt(int* cnt, int N) {
    int i = blockIdx.x * 256 + threadIdx.x;
    if (i < N) cnt[i] = 0;
}

__global__ void k_count(const int* __restrict__ src, const int* __restrict__ dst,
                        int* __restrict__ cnt, int E, int N) {
    int e = blockIdx.x * 256 + threadIdx.x;
    if (e >= E) return;
    int s = src[e], d = dst[e];
    if ((unsigned)s < (unsigned)N && (unsigned)d < (unsigned)N) atomicAdd(&cnt[d], 1);
}

#define SCAN_B 256
// also emits dis[i] = rsqrt(deg+1) (fused, saves a launch)
__global__ void k_scan_a(const int* __restrict__ cnt, int* __restrict__ rowptr,
                         int* __restrict__ bsum, float* __restrict__ dis, int N) {
    __shared__ int sh[SCAN_B];
    int t = threadIdx.x, i = blockIdx.x * SCAN_B + t;
    int v = (i < N) ? cnt[i] : 0;
    if (i < N) dis[i] = rsqrtf((float)(v + 1));   // +1 self loop
    sh[t] = v; __syncthreads();
    for (int off = 1; off < SCAN_B; off <<= 1) {
        int x = (t >= off) ? sh[t - off] : 0;
        __syncthreads();
        sh[t] += x;
        __syncthreads();
    }
    int incl = sh[t];
    if (i < N) rowptr[i] = incl - v;
    if (t == SCAN_B - 1) bsum[blockIdx.x] = incl;
}

__global__ void k_scan_b(int* bsum, int NB) {
    __shared__ int sh[512];
    int t = threadIdx.x;
    int v = (t < NB) ? bsum[t] : 0;
    sh[t] = v; __syncthreads();
    for (int off = 1; off < 512; off <<= 1) {
        int x = (t >= off) ? sh[t - off] : 0;
        __syncthreads();
        sh[t] += x;
        __syncthreads();
    }
    if (t < NB) bsum[t] = sh[t] - v;
}

__global__ void k_scan_c(int* __restrict__ rowptr, int* __restrict__ cursor,
                         const int* __restrict__ bsum, int N) {
    int i = blockIdx.x * 256 + threadIdx.x;
    if (i < N) {
        int r = rowptr[i] + bsum[blockIdx.x];
        rowptr[i] = r;
        cursor[i] = r;
    }
}

// 4-byte scatter: src index only (w recomputed in agg from dis[])
__global__ void k_fill(const int* __restrict__ src, const int* __restrict__ dst,
                       int* __restrict__ cursor, int* __restrict__ csrc, int E, int N) {
    int e = blockIdx.x * 256 + threadIdx.x;
    if (e >= E) return;
    int s = src[e], d = dst[e];
    if ((unsigned)s >= (unsigned)N || (unsigned)d >= (unsigned)N) return;
    int p = atomicAdd(&cursor[d], 1);
    csrc[p] = s;
}

// ---------- GEMM (layer 1): H[N][128](bf16) = X[N][128](fp32) @ W[128][128](fp32) ----------
__global__ __launch_bounds__(256)
void k_gemm128_a32(const float* __restrict__ X,
                   const float* __restrict__ W,
                   unsigned short* __restrict__ H, int nPairs) {
    int wave = threadIdx.x >> 6;
    int lane = threadIdx.x & 63;
    int ln = lane & 15, quad = lane >> 4;
    int c0 = (wave & 1) * 64;
    int subTile = wave >> 1;

    sh8 bh[4][4], blo[4][4];   // [nt][kt]
    #pragma unroll
    for (int nt = 0; nt < 4; ++nt) {
        int col = c0 + nt * 16 + ln;
        #pragma unroll
        for (int kt = 0; kt < 4; ++kt) {
            int k0 = kt * 32 + quad * 8;
            #pragma unroll
            for (int j = 0; j < 8; ++j) {
                short h, l;
                bfsplit(W[(k0 + j) * 128 + col], h, l);
                bh[nt][kt][j] = h; blo[nt][kt][j] = l;
            }
        }
    }

    for (int p = blockIdx.x; p < nPairs; p += gridDim.x) {
        int nodeBase = p * 32 + subTile * 16;
        const float* xrow = X + (nodeBase + ln) * 128 + quad * 8;
        sh8 ah[4], al[4];
        #pragma unroll
        for (int kt = 0; kt < 4; ++kt) {
            f4 v0 = *(const f4*)(xrow + kt * 32);
            f4 v1 = *(const f4*)(xrow + kt * 32 + 4);
            #pragma unroll
            for (int j = 0; j < 4; ++j) {
                short h, l;
                bfsplit(v0[j], h, l); ah[kt][j] = h; al[kt][j] = l;
                bfsplit(v1[j], h, l); ah[kt][j + 4] = h; al[kt][j + 4] = l;
            }
        }

        f4 acc[4] = { {0.f,0.f,0.f,0.f}, {0.f,0.f,0.f,0.f}, {0.f,0.f,0.f,0.f}, {0.f,0.f,0.f,0.f} };
        #pragma unroll
        for (int kt = 0; kt < 4; ++kt)
            #pragma unroll
            for (int nt = 0; nt < 4; ++nt) {
                acc[nt] = __builtin_amdgcn_mfma_f32_16x16x32_bf16(ah[kt], bh[nt][kt], acc[nt], 0, 0, 0);
                acc[nt] = __builtin_amdgcn_mfma_f32_16x16x32_bf16(ah[kt], blo[nt][kt], acc[nt], 0, 0, 0);
                acc[nt] = __builtin_amdgcn_mfma_f32_16x16x32_bf16(al[kt], bh[nt][kt], acc[nt], 0, 0, 0);
            }

        #pragma unroll
        for (int nt = 0; nt < 4; ++nt) {
            int col = c0 + nt * 16 + ln;
            #pragma unroll
            for (int r = 0; r < 4; ++r)
                H[(nodeBase + quad * 4 + r) * 128 + col] = f2bf(acc[nt][r]);
        }
    }
}

// ---------- GEMM (layers 2,3): H(bf16) = X(bf16) @ W(fp32, split) ----------
__global__ __launch_bounds__(256)
void k_gemm128_a16(const unsigned short* __restrict__ X,
                   const float* __restrict__ W,
                   unsigned short* __restrict__ H, int nPairs) {
    int wave = threadIdx.x >> 6;
    int lane = threadIdx.x & 63;
    int ln = lane & 15, quad = lane >> 4;
    int c0 = (wave & 1) * 64;
    int subTile = wave >> 1;

    sh8 bh[4][4], blo[4][4];
    #pragma unroll
    for (int nt = 0; nt < 4; ++nt) {
        int col = c0 + nt * 16 + ln;
        #pragma unroll
        for (int kt = 0; kt < 4; ++kt) {
            int k0 = kt * 32 + quad * 8;
            #pragma unroll
            for (int j = 0; j < 8; ++j) {
                short h, l;
                bfsplit(W[(k0 + j) * 128 + col], h, l);
                bh[nt][kt][j] = h; blo[nt][kt][j] = l;
            }
        }
    }

    for (int p = blockIdx.x; p < nPairs; p += gridDim.x) {
        int nodeBase = p * 32 + subTile * 16;
        const unsigned short* xrow = X + (nodeBase + ln) * 128 + quad * 8;
        sh8 a[4];
        #pragma unroll
        for (int kt = 0; kt < 4; ++kt) a[kt] = *(const sh8*)(xrow + kt * 32);

        f4 acc[4] = { {0.f,0.f,0.f,0.f}, {0.f,0.f,0.f,0.f}, {0.f,0.f,0.f,0.f}, {0.f,0.f,0.f,0.f} };
        #pragma unroll
        for (int kt = 0; kt < 4; ++kt)
            #pragma unroll
            for (int nt = 0; nt < 4; ++nt) {
                acc[nt] = __builtin_amdgcn_mfma_f32_16x16x32_bf16(a[kt], bh[nt][kt], acc[nt], 0, 0, 0);
                acc[nt] = __builtin_amdgcn_mfma_f32_16x16x32_bf16(a[kt], blo[nt][kt], acc[nt], 0, 0, 0);
            }

        #pragma unroll
        for (int nt = 0; nt < 4; ++nt) {
            int col = c0 + nt * 16 + ln;
            #pragma unroll
            for (int r = 0; r < 4; ++r)
                H[(nodeBase + quad * 4 + r) * 128 + col] = f2bf(acc[nt][r]);
        }
    }
}

// ---------- Aggregation: O(bf16) = bias + relu?( sum_e dis[s]*dis[n]*H[s] + dis[n]^2*H[n] ) ----------
// One wave/node, 64 lanes x 2 bf16 feats. 4-wide ILP: 4 independent src loads ->
// 4 independent dis loads + 4 independent 256B row gathers per iteration.
__global__ __launch_bounds__(256)
void k_agg(const unsigned short* __restrict__ H,
           unsigned short* __restrict__ O,
           const float* __restrict__ dis,
           const int* __restrict__ rowptr,
           const int* __restrict__ cnt,
           const int* __restrict__ csrc,
           const float* __restrict__ bias,
           int relu, int N) {
    int n = (blockIdx.x * 256 + threadIdx.x) >> 6;
    int lane = threadIdx.x & 63;
    if (n >= N) return;
    int c = lane * 2;

    float dn = dis[n];
    unsigned int hv = *(const unsigned int*)(H + n * 128 + c);
    float a0 = bf2f((unsigned short)hv) * dn * dn;
    float a1 = bf2f((unsigned short)(hv >> 16)) * dn * dn;

    int start = rowptr[n];
    int e = cnt[n];
    int i = 0;
    for (; i + 4 <= e; i += 4) {
        int s0 = csrc[start + i];
        int s1 = csrc[start + i + 1];
        int s2 = csrc[start + i + 2];
        int s3 = csrc[start + i + 3];
        unsigned int v0 = *(const unsigned int*)(H + s0 * 128 + c);
        unsigned int v1 = *(const unsigned int*)(H + s1 * 128 + c);
        unsigned int v2 = *(const unsigned int*)(H + s2 * 128 + c);
        unsigned int v3 = *(const unsigned int*)(H + s3 * 128 + c);
        float w0 = dis[s0] * dn;
        float w1 = dis[s1] * dn;
        float w2 = dis[s2] * dn;
        float w3 = dis[s3] * dn;
        a0 += w0 * bf2f((unsigned short)v0);
        a1 += w0 * bf2f((unsigned short)(v0 >> 16));
        a0 += w1 * bf2f((unsigned short)v1);
        a1 += w1 * bf2f((unsigned short)(v1 >> 16));
        a0 += w2 * bf2f((unsigned short)v2);
        a1 += w2 * bf2f((unsigned short)(v2 >> 16));
        a0 += w3 * bf2f((unsigned short)v3);
        a1 += w3 * bf2f((unsigned short)(v3 >> 16));
    }
    for (; i < e; ++i) {
        int s0 = csrc[start + i];
        unsigned int v0 = *(const unsigned int*)(H + s0 * 128 + c);
        float w0 = dis[s0] * dn;
        a0 += w0 * bf2f((unsigned short)v0);
        a1 += w0 * bf2f((unsigned short)(v0 >> 16));
    }

    a0 += bias[c];
    a1 += bias[c + 1];
    if (relu) { a0 = fmaxf(a0, 0.f); a1 = fmaxf(a1, 0.f); }

    unsigned int ov = (unsigned int)f2bf(a0) | ((unsigned int)f2bf(a1) << 16);
    *(unsigned int*)(O + n * 128 + c) = ov;
}

// ---------- Final head: OUT[N][40](fp32) = X(bf16) @ Wl(fp32 split) + bl ----------
__global__ __launch_bounds__(256)
void k_gemm_final(const unsigned short* __restrict__ X,
                  const float* __restrict__ W,     // [128][40]
                  const float* __restrict__ bl,    // [40]
                  float* __restrict__ OUT, int nTiles) {
    int wave = threadIdx.x >> 6;
    int lane = threadIdx.x & 63;
    int ln = lane & 15, quad = lane >> 4;
    int tile = blockIdx.x * 4 + wave;
    if (tile >= nTiles) return;

    sh8 bh[3][4], blo[3][4];
    #pragma unroll
    for (int nt = 0; nt < 3; ++nt) {
        int col = nt * 16 + ln;
        bool valid = (col < 40);
        #pragma unroll
        for (int kt = 0; kt < 4; ++kt) {
            int k0 = kt * 32 + quad * 8;
            #pragma unroll
            for (int j = 0; j < 8; ++j) {
                short h = 0, l = 0;
                if (valid) bfsplit(W[(k0 + j) * 40 + col], h, l);
                bh[nt][kt][j] = h; blo[nt][kt][j] = l;
            }
        }
    }

    int nodeBase = tile * 16;
    const unsigned short* xrow = X + (nodeBase + ln) * 128 + quad * 8;
    sh8 a[4];
    #pragma unroll
    for (int kt = 0; kt < 4; ++kt) a[kt] = *(const sh8*)(xrow + kt * 32);

    f4 acc[3] = { {0.f,0.f,0.f,0.f}, {0.f,0.f,0.f,0.f}, {0.f,0.f,0.f,0.f} };
    #pragma unroll
    for (int kt = 0; kt < 4; ++kt)
        #pragma unroll
        for (int nt = 0; nt < 3; ++nt) {
            acc[nt] = __builtin_amdgcn_mfma_f32_16x16x32_bf16(a[kt], bh[nt][kt], acc[nt], 0, 0, 0);
            acc[nt] = __builtin_amdgcn_mfma_f32_16x16x32_bf16(a[kt], blo[nt][kt], acc[nt], 0, 0, 0);
        }

    #pragma unroll
    for (int nt = 0; nt < 3; ++nt) {
        int col = nt * 16 + ln;
        if (col < 40) {
            float bv = bl[col];
            #pragma unroll
            for (int r = 0; r < 4; ++r)
                OUT[(nodeBase + quad * 4 + r) * 40 + col] = acc[nt][r] + bv;
        }
    }
}

// ---------- launch ----------
extern "C" void kernel_launch(void* const* d_in, const int* in_sizes, int n_in,
                              void* d_out, int out_size, void* d_ws, size_t ws_size,
                              hipStream_t stream) {
    const float* x  = (const float*)d_in[0];
    const int*   ei = (const int*)d_in[1];
    const float* W1 = (const float*)d_in[2];
    const float* b1 = (const float*)d_in[3];
    const float* W2 = (const float*)d_in[4];
    const float* b2 = (const float*)d_in[5];
    const float* W3 = (const float*)d_in[6];
    const float* b3 = (const float*)d_in[7];
    const float* Wl = (const float*)d_in[8];
    const float* bl = (const float*)d_in[9];

    const int N = in_sizes[0] / 128;   // 100000
    const int E = in_sizes[1] / 2;     // 1600000
    const int* srcIdx = ei;
    const int* dstIdx = ei + E;

    char* ws = (char*)d_ws;
    size_t off = 0;
    auto alloc = [&](size_t bytes) { void* p = ws + off; off += (bytes + 511) & ~(size_t)511; return p; };
    int*   cnt     = (int*)  alloc((size_t)N * 4);
    int*   rowptr  = (int*)  alloc((size_t)N * 4);
    int*   cursor  = (int*)  alloc((size_t)N * 4);
    float* dis     = (float*)alloc((size_t)N * 4);
    int*   bsum    = (int*)  alloc(512 * 4);
    int*   csrc    = (int*)  alloc((size_t)E * 4);
    unsigned short* h0 = (unsigned short*)alloc((size_t)N * 128 * 2);
    unsigned short* h1 = (unsigned short*)alloc((size_t)N * 128 * 2);

    const int gN = (N + 255) / 256;           // 391
    const int gE = (E + 255) / 256;           // 6250
    const int nPairs = N / 32;                // 3125
    const int nTiles = N / 16;                // 6250
    const int gAgg = (N * 64) / 256;          // 25000

    // CSR build
    k_zero_cnt<<<gN, 256, 0, stream>>>(cnt, N);
    k_count<<<gE, 256, 0, stream>>>(srcIdx, dstIdx, cnt, E, N);
    k_scan_a<<<gN, 256, 0, stream>>>(cnt, rowptr, bsum, dis, N);
    k_scan_b<<<1, 512, 0, stream>>>(bsum, gN);
    k_scan_c<<<gN, 256, 0, stream>>>(rowptr, cursor, bsum, N);
    k_fill<<<gE, 256, 0, stream>>>(srcIdx, dstIdx, cursor, csrc, E, N);

    // Layer 1
    k_gemm128_a32<<<768, 256, 0, stream>>>(x, W1, h0, nPairs);
    k_agg<<<gAgg, 256, 0, stream>>>(h0, h1, dis, rowptr, cnt, csrc, b1, 1, N);
    // Layer 2
    k_gemm128_a16<<<768, 256, 0, stream>>>(h1, W2, h0, nPairs);
    k_agg<<<gAgg, 256, 0, stream>>>(h0, h1, dis, rowptr, cnt, csrc, b2, 1, N);
    // Layer 3 (no relu)
    k_gemm128_a16<<<768, 256, 0, stream>>>(h1, W3, h0, nPairs);
    k_agg<<<gAgg, 256, 0, stream>>>(h0, h1, dis, rowptr, cnt, csrc, b3, 0, N);
    // Head
    k_gemm_final<<<(nTiles + 3) / 4, 256, 0, stream>>>(h1, Wl, bl, (float*)d_out, nTiles);
}

// Round 5
// 549.702 us; speedup vs baseline: 1.7689x; 1.1191x over previous
//
#include <hip/hip_runtime.h>

// ---------- types & helpers ----------
typedef __attribute__((ext_vector_type(8))) short sh8;   // 8 x bf16 (4 VGPRs)
typedef __attribute__((ext_vector_type(4))) float f4;    // MFMA accum / float4

__device__ __forceinline__ float bf2f(unsigned short u) {
    union { unsigned int u; float f; } c; c.u = ((unsigned int)u) << 16; return c.f;
}
__device__ __forceinline__ unsigned short f2bf(float f) {
    union { float f; unsigned int u; } c; c.f = f;
    unsigned int x = c.u;
    unsigned int r = (x + 0x7fffu + ((x >> 16) & 1u)) >> 16;   // RNE
    return (unsigned short)r;
}
// split fp32 into bf16 hi + bf16 lo (residual)
__device__ __forceinline__ void bfsplit(float x, short& hi, short& lo) {
    unsigned short h = f2bf(x);
    float r = x - bf2f(h);
    hi = (short)h;
    lo = (short)f2bf(r);
}

// ---------- CSR build ----------
__global__ void k_zero_cnt(int* cnt, int N) {
    int i = blockIdx.x * 256 + threadIdx.x;
    if (i < N) cnt[i] = 0;
}

// XCD-partitioned count: group g = blockIdx&7 handles dst range [g*N/8,(g+1)*N/8).
// Each group strides the full edge list; cnt atomics stay in one XCD's L2 slice.
__global__ void k_count(const int* __restrict__ dst, int* __restrict__ cnt, int E, int N) {
    int g = blockIdx.x & 7;
    int j = blockIdx.x >> 3;
    int nb = gridDim.x >> 3;
    int lo = (int)((long long)g * N / 8);
    int hi = (int)((long long)(g + 1) * N / 8);
    for (int e = j * 256 + threadIdx.x; e < E; e += nb * 256) {
        int d = dst[e];
        if (d >= lo && d < hi) atomicAdd(&cnt[d], 1);
    }
}

#define SCAN_B 256
// also emits dis[i] = rsqrt(deg+1) (fused)
__global__ void k_scan_a(const int* __restrict__ cnt, int* __restrict__ rowptr,
                         int* __restrict__ bsum, float* __restrict__ dis, int N) {
    __shared__ int sh[SCAN_B];
    int t = threadIdx.x, i = blockIdx.x * SCAN_B + t;
    int v = (i < N) ? cnt[i] : 0;
    if (i < N) dis[i] = rsqrtf((float)(v + 1));   // +1 self loop
    sh[t] = v; __syncthreads();
    for (int off = 1; off < SCAN_B; off <<= 1) {
        int x = (t >= off) ? sh[t - off] : 0;
        __syncthreads();
        sh[t] += x;
        __syncthreads();
    }
    int incl = sh[t];
    if (i < N) rowptr[i] = incl - v;
    if (t == SCAN_B - 1) bsum[blockIdx.x] = incl;
}

__global__ void k_scan_b(int* bsum, int NB) {
    __shared__ int sh[512];
    int t = threadIdx.x;
    int v = (t < NB) ? bsum[t] : 0;
    sh[t] = v; __syncthreads();
    for (int off = 1; off < 512; off <<= 1) {
        int x = (t >= off) ? sh[t - off] : 0;
        __syncthreads();
        sh[t] += x;
        __syncthreads();
    }
    if (t < NB) bsum[t] = sh[t] - v;
}

__global__ void k_scan_c(int* __restrict__ rowptr, int* __restrict__ cursor,
                         const int* __restrict__ bsum, int N) {
    int i = blockIdx.x * 256 + threadIdx.x;
    if (i < N) {
        int r = rowptr[i] + bsum[blockIdx.x];
        rowptr[i] = r;
        cursor[i] = r;
    }
}

// XCD-partitioned fill: group g writes only dst in its range -> csrc positions land in
// one contiguous ~E/8*4B region whose lines are written by one XCD close in time -> L2-merged.
__global__ void k_fill(const int* __restrict__ src, const int* __restrict__ dst,
                       int* __restrict__ cursor, int* __restrict__ csrc, int E, int N) {
    int g = blockIdx.x & 7;
    int j = blockIdx.x >> 3;
    int nb = gridDim.x >> 3;
    int lo = (int)((long long)g * N / 8);
    int hi = (int)((long long)(g + 1) * N / 8);
    for (int e = j * 256 + threadIdx.x; e < E; e += nb * 256) {
        int d = dst[e];
        if (d < lo || d >= hi) continue;
        int s = src[e];
        if ((unsigned)s >= (unsigned)N) continue;
        int p = atomicAdd(&cursor[d], 1);
        csrc[p] = s;
    }
}

// ---------- GEMM (layer 1): H[N][128](bf16) = X[N][128](fp32) @ W[128][128](fp32) ----------
__global__ __launch_bounds__(256)
void k_gemm128_a32(const float* __restrict__ X,
                   const float* __restrict__ W,
                   unsigned short* __restrict__ H, int nPairs) {
    int wave = threadIdx.x >> 6;
    int lane = threadIdx.x & 63;
    int ln = lane & 15, quad = lane >> 4;
    int c0 = (wave & 1) * 64;
    int subTile = wave >> 1;

    sh8 bh[4][4], blo[4][4];   // [nt][kt]
    #pragma unroll
    for (int nt = 0; nt < 4; ++nt) {
        int col = c0 + nt * 16 + ln;
        #pragma unroll
        for (int kt = 0; kt < 4; ++kt) {
            int k0 = kt * 32 + quad * 8;
            #pragma unroll
            for (int j = 0; j < 8; ++j) {
                short h, l;
                bfsplit(W[(k0 + j) * 128 + col], h, l);
                bh[nt][kt][j] = h; blo[nt][kt][j] = l;
            }
        }
    }

    for (int p = blockIdx.x; p < nPairs; p += gridDim.x) {
        int nodeBase = p * 32 + subTile * 16;
        const float* xrow = X + (nodeBase + ln) * 128 + quad * 8;
        sh8 ah[4], al[4];
        #pragma unroll
        for (int kt = 0; kt < 4; ++kt) {
            f4 v0 = *(const f4*)(xrow + kt * 32);
            f4 v1 = *(const f4*)(xrow + kt * 32 + 4);
            #pragma unroll
            for (int j = 0; j < 4; ++j) {
                short h, l;
                bfsplit(v0[j], h, l); ah[kt][j] = h; al[kt][j] = l;
                bfsplit(v1[j], h, l); ah[kt][j + 4] = h; al[kt][j + 4] = l;
            }
        }

        f4 acc[4] = { {0.f,0.f,0.f,0.f}, {0.f,0.f,0.f,0.f}, {0.f,0.f,0.f,0.f}, {0.f,0.f,0.f,0.f} };
        #pragma unroll
        for (int kt = 0; kt < 4; ++kt)
            #pragma unroll
            for (int nt = 0; nt < 4; ++nt) {
                acc[nt] = __builtin_amdgcn_mfma_f32_16x16x32_bf16(ah[kt], bh[nt][kt], acc[nt], 0, 0, 0);
                acc[nt] = __builtin_amdgcn_mfma_f32_16x16x32_bf16(ah[kt], blo[nt][kt], acc[nt], 0, 0, 0);
                acc[nt] = __builtin_amdgcn_mfma_f32_16x16x32_bf16(al[kt], bh[nt][kt], acc[nt], 0, 0, 0);
            }

        #pragma unroll
        for (int nt = 0; nt < 4; ++nt) {
            int col = c0 + nt * 16 + ln;
            #pragma unroll
            for (int r = 0; r < 4; ++r)
                H[(nodeBase + quad * 4 + r) * 128 + col] = f2bf(acc[nt][r]);
        }
    }
}

// ---------- GEMM (layers 2,3): H(bf16) = X(bf16) @ W(fp32, split) ----------
__global__ __launch_bounds__(256)
void k_gemm128_a16(const unsigned short* __restrict__ X,
                   const float* __restrict__ W,
                   unsigned short* __restrict__ H, int nPairs) {
    int wave = threadIdx.x >> 6;
    int lane = threadIdx.x & 63;
    int ln = lane & 15, quad = lane >> 4;
    int c0 = (wave & 1) * 64;
    int subTile = wave >> 1;

    sh8 bh[4][4], blo[4][4];
    #pragma unroll
    for (int nt = 0; nt < 4; ++nt) {
        int col = c0 + nt * 16 + ln;
        #pragma unroll
        for (int kt = 0; kt < 4; ++kt) {
            int k0 = kt * 32 + quad * 8;
            #pragma unroll
            for (int j = 0; j < 8; ++j) {
                short h, l;
                bfsplit(W[(k0 + j) * 128 + col], h, l);
                bh[nt][kt][j] = h; blo[nt][kt][j] = l;
            }
        }
    }

    for (int p = blockIdx.x; p < nPairs; p += gridDim.x) {
        int nodeBase = p * 32 + subTile * 16;
        const unsigned short* xrow = X + (nodeBase + ln) * 128 + quad * 8;
        sh8 a[4];
        #pragma unroll
        for (int kt = 0; kt < 4; ++kt) a[kt] = *(const sh8*)(xrow + kt * 32);

        f4 acc[4] = { {0.f,0.f,0.f,0.f}, {0.f,0.f,0.f,0.f}, {0.f,0.f,0.f,0.f}, {0.f,0.f,0.f,0.f} };
        #pragma unroll
        for (int kt = 0; kt < 4; ++kt)
            #pragma unroll
            for (int nt = 0; nt < 4; ++nt) {
                acc[nt] = __builtin_amdgcn_mfma_f32_16x16x32_bf16(a[kt], bh[nt][kt], acc[nt], 0, 0, 0);
                acc[nt] = __builtin_amdgcn_mfma_f32_16x16x32_bf16(a[kt], blo[nt][kt], acc[nt], 0, 0, 0);
            }

        #pragma unroll
        for (int nt = 0; nt < 4; ++nt) {
            int col = c0 + nt * 16 + ln;
            #pragma unroll
            for (int r = 0; r < 4; ++r)
                H[(nodeBase + quad * 4 + r) * 128 + col] = f2bf(acc[nt][r]);
        }
    }
}

// ---------- Aggregation: O(bf16) = bias + relu?( sum_e dis[s]*dis[n]*H[s] + dis[n]^2*H[n] ) ----------
// One wave/node, 64 lanes x 2 bf16 feats. 8-wide ILP gather loop.
__global__ __launch_bounds__(256)
void k_agg(const unsigned short* __restrict__ H,
           unsigned short* __restrict__ O,
           const float* __restrict__ dis,
           const int* __restrict__ rowptr,
           const int* __restrict__ cnt,
           const int* __restrict__ csrc,
           const float* __restrict__ bias,
           int relu, int N) {
    int n = (blockIdx.x * 256 + threadIdx.x) >> 6;
    int lane = threadIdx.x & 63;
    if (n >= N) return;
    int c = lane * 2;

    float dn = dis[n];
    unsigned int hv = *(const unsigned int*)(H + n * 128 + c);
    float a0 = bf2f((unsigned short)hv) * dn * dn;
    float a1 = bf2f((unsigned short)(hv >> 16)) * dn * dn;

    int start = rowptr[n];
    int e = cnt[n];
    int i = 0;
    for (; i + 8 <= e; i += 8) {
        int s[8];
        #pragma unroll
        for (int q = 0; q < 8; ++q) s[q] = csrc[start + i + q];
        unsigned int v[8];
        #pragma unroll
        for (int q = 0; q < 8; ++q) v[q] = *(const unsigned int*)(H + (size_t)s[q] * 128 + c);
        float w[8];
        #pragma unroll
        for (int q = 0; q < 8; ++q) w[q] = dis[s[q]] * dn;
        #pragma unroll
        for (int q = 0; q < 8; ++q) {
            a0 += w[q] * bf2f((unsigned short)v[q]);
            a1 += w[q] * bf2f((unsigned short)(v[q] >> 16));
        }
    }
    if (i + 4 <= e) {
        int s[4];
        #pragma unroll
        for (int q = 0; q < 4; ++q) s[q] = csrc[start + i + q];
        unsigned int v[4];
        #pragma unroll
        for (int q = 0; q < 4; ++q) v[q] = *(const unsigned int*)(H + (size_t)s[q] * 128 + c);
        #pragma unroll
        for (int q = 0; q < 4; ++q) {
            float w = dis[s[q]] * dn;
            a0 += w * bf2f((unsigned short)v[q]);
            a1 += w * bf2f((unsigned short)(v[q] >> 16));
        }
        i += 4;
    }
    for (; i < e; ++i) {
        int s0 = csrc[start + i];
        unsigned int v0 = *(const unsigned int*)(H + (size_t)s0 * 128 + c);
        float w0 = dis[s0] * dn;
        a0 += w0 * bf2f((unsigned short)v0);
        a1 += w0 * bf2f((unsigned short)(v0 >> 16));
    }

    a0 += bias[c];
    a1 += bias[c + 1];
    if (relu) { a0 = fmaxf(a0, 0.f); a1 = fmaxf(a1, 0.f); }

    unsigned int ov = (unsigned int)f2bf(a0) | ((unsigned int)f2bf(a1) << 16);
    *(unsigned int*)(O + n * 128 + c) = ov;
}

// ---------- Final head: OUT[N][40](fp32) = X(bf16) @ Wl(fp32 split) + bl ----------
__global__ __launch_bounds__(256)
void k_gemm_final(const unsigned short* __restrict__ X,
                  const float* __restrict__ W,     // [128][40]
                  const float* __restrict__ bl,    // [40]
                  float* __restrict__ OUT, int nTiles) {
    int wave = threadIdx.x >> 6;
    int lane = threadIdx.x & 63;
    int ln = lane & 15, quad = lane >> 4;
    int tile = blockIdx.x * 4 + wave;
    if (tile >= nTiles) return;

    sh8 bh[3][4], blo[3][4];
    #pragma unroll
    for (int nt = 0; nt < 3; ++nt) {
        int col = nt * 16 + ln;
        bool valid = (col < 40);
        #pragma unroll
        for (int kt = 0; kt < 4; ++kt) {
            int k0 = kt * 32 + quad * 8;
            #pragma unroll
            for (int j = 0; j < 8; ++j) {
                short h = 0, l = 0;
                if (valid) bfsplit(W[(k0 + j) * 40 + col], h, l);
                bh[nt][kt][j] = h; blo[nt][kt][j] = l;
            }
        }
    }

    int nodeBase = tile * 16;
    const unsigned short* xrow = X + (nodeBase + ln) * 128 + quad * 8;
    sh8 a[4];
    #pragma unroll
    for (int kt = 0; kt < 4; ++kt) a[kt] = *(const sh8*)(xrow + kt * 32);

    f4 acc[3] = { {0.f,0.f,0.f,0.f}, {0.f,0.f,0.f,0.f}, {0.f,0.f,0.f,0.f} };
    #pragma unroll
    for (int kt = 0; kt < 4; ++kt)
        #pragma unroll
        for (int nt = 0; nt < 3; ++nt) {
            acc[nt] = __builtin_amdgcn_mfma_f32_16x16x32_bf16(a[kt], bh[nt][kt], acc[nt], 0, 0, 0);
            acc[nt] = __builtin_amdgcn_mfma_f32_16x16x32_bf16(a[kt], blo[nt][kt], acc[nt], 0, 0, 0);
        }

    #pragma unroll
    for (int nt = 0; nt < 3; ++nt) {
        int col = nt * 16 + ln;
        if (col < 40) {
            float bv = bl[col];
            #pragma unroll
            for (int r = 0; r < 4; ++r)
                OUT[(nodeBase + quad * 4 + r) * 40 + col] = acc[nt][r] + bv;
        }
    }
}

// ---------- launch ----------
extern "C" void kernel_launch(void* const* d_in, const int* in_sizes, int n_in,
                              void* d_out, int out_size, void* d_ws, size_t ws_size,
                              hipStream_t stream) {
    const float* x  = (const float*)d_in[0];
    const int*   ei = (const int*)d_in[1];
    const float* W1 = (const float*)d_in[2];
    const float* b1 = (const float*)d_in[3];
    const float* W2 = (const float*)d_in[4];
    const float* b2 = (const float*)d_in[5];
    const float* W3 = (const float*)d_in[6];
    const float* b3 = (const float*)d_in[7];
    const float* Wl = (const float*)d_in[8];
    const float* bl = (const float*)d_in[9];

    const int N = in_sizes[0] / 128;   // 100000
    const int E = in_sizes[1] / 2;     // 1600000
    const int* srcIdx = ei;
    const int* dstIdx = ei + E;

    char* ws = (char*)d_ws;
    size_t off = 0;
    auto alloc = [&](size_t bytes) { void* p = ws + off; off += (bytes + 511) & ~(size_t)511; return p; };
    int*   cnt     = (int*)  alloc((size_t)N * 4);
    int*   rowptr  = (int*)  alloc((size_t)N * 4);
    int*   cursor  = (int*)  alloc((size_t)N * 4);
    float* dis     = (float*)alloc((size_t)N * 4);
    int*   bsum    = (int*)  alloc(512 * 4);
    int*   csrc    = (int*)  alloc((size_t)E * 4);
    unsigned short* h0 = (unsigned short*)alloc((size_t)N * 128 * 2);
    unsigned short* h1 = (unsigned short*)alloc((size_t)N * 128 * 2);

    const int gN = (N + 255) / 256;           // 391
    const int nPairs = N / 32;                // 3125
    const int nTiles = N / 16;                // 6250
    const int gAgg = (N * 64) / 256;          // 25000
    const int gPart = 1024;                   // 8 XCD groups x 128 blocks

    // CSR build (k_count / k_fill are XCD-partitioned by dst range)
    k_zero_cnt<<<gN, 256, 0, stream>>>(cnt, N);
    k_count<<<gPart, 256, 0, stream>>>(dstIdx, cnt, E, N);
    k_scan_a<<<gN, 256, 0, stream>>>(cnt, rowptr, bsum, dis, N);
    k_scan_b<<<1, 512, 0, stream>>>(bsum, gN);
    k_scan_c<<<gN, 256, 0, stream>>>(rowptr, cursor, bsum, N);
    k_fill<<<gPart, 256, 0, stream>>>(srcIdx, dstIdx, cursor, csrc, E, N);

    // Layer 1
    k_gemm128_a32<<<768, 256, 0, stream>>>(x, W1, h0, nPairs);
    k_agg<<<gAgg, 256, 0, stream>>>(h0, h1, dis, rowptr, cnt, csrc, b1, 1, N);
    // Layer 2
    k_gemm128_a16<<<768, 256, 0, stream>>>(h1, W2, h0, nPairs);
    k_agg<<<gAgg, 256, 0, stream>>>(h0, h1, dis, rowptr, cnt, csrc, b2, 1, N);
    // Layer 3 (no relu)
    k_gemm128_a16<<<768, 256, 0, stream>>>(h1, W3, h0, nPairs);
    k_agg<<<gAgg, 256, 0, stream>>>(h0, h1, dis, rowptr, cnt, csrc, b3, 0, N);
    // Head
    k_gemm_final<<<(nTiles + 3) / 4, 256, 0, stream>>>(h1, Wl, bl, (float*)d_out, nTiles);
}